// Round 1
// baseline (17141.002 us; speedup 1.0000x reference)
//
#include <hip/hip_runtime.h>
#include <hip/hip_bf16.h>

// LSTM persistent kernel, MI355X.
// B=64, T=2048, D=64, H=512, O=128. K = D+H = 576.
// Grid: 128 WGs x 64 threads (1 wave). WG = (batch-group bg of 16 rows) x (gate-group gi of 16 hidden dims).
// Weights stationary in VGPRs (288/lane). h broadcast via ws (bf16, double-buffered),
// per-step per-group barrier via atomic counters (release/acquire, agent scope — cross-XCD safe).

typedef short short8 __attribute__((ext_vector_type(8)));
typedef float floatx4 __attribute__((ext_vector_type(4)));

#define T_STEPS 2048
#define NGROUP 4
#define NGATE  32

__device__ __forceinline__ unsigned short f2bf(float f){
    unsigned u = __builtin_bit_cast(unsigned, f);
    u += 0x7FFFu + ((u >> 16) & 1u);   // RNE; inputs finite
    return (unsigned short)(u >> 16);
}

__device__ __forceinline__ short8 pack8(float4 a, float4 b){
    short8 s;
    s[0]=(short)f2bf(a.x); s[1]=(short)f2bf(a.y); s[2]=(short)f2bf(a.z); s[3]=(short)f2bf(a.w);
    s[4]=(short)f2bf(b.x); s[5]=(short)f2bf(b.y); s[6]=(short)f2bf(b.z); s[7]=(short)f2bf(b.w);
    return s;
}

__device__ __forceinline__ float fsigmoid(float x){
    return 1.0f / (1.0f + __expf(-x));
}
__device__ __forceinline__ float ftanh(float x){
    return 2.0f * fsigmoid(2.0f * x) - 1.0f;
}

__global__ __launch_bounds__(64, 1)
void lstm_persist(const float* __restrict__ x,
                  const float* __restrict__ W_ih,
                  const float* __restrict__ W_hh,
                  const float* __restrict__ b_ih,
                  const float* __restrict__ b_hh,
                  const float* __restrict__ W_out,
                  const float* __restrict__ b_out,
                  float* __restrict__ out,
                  unsigned short* __restrict__ hbuf,  // [2][NGROUP][16][512] bf16
                  unsigned* __restrict__ cnt)         // [NGROUP][T_STEPS]
{
    const int wg   = blockIdx.x;
    const int bg   = wg >> 5;        // batch group (16 rows)
    const int gi   = wg & 31;        // gate group (16 hidden dims)
    const int lane = threadIdx.x;    // 0..63
    const int ln   = lane & 15;
    const int lk   = lane >> 4;      // k-chunk 0..3
    const int hd0  = gi << 4;

    // ---- stationary B fragments (weights) in registers ----
    // tile g = gate type (i,f,g,o): W rows g*512 + hd0 + ln; k = kk*32 + lk*8 + j
    short8 bw[4][18];
#pragma unroll
    for (int g = 0; g < 4; ++g){
        const int row = g * 512 + hd0 + ln;
        const float* pih = W_ih + row * 64 + lk * 8;
#pragma unroll
        for (int kk = 0; kk < 2; ++kk){
            float4 u0 = *reinterpret_cast<const float4*>(pih + kk * 32);
            float4 u1 = *reinterpret_cast<const float4*>(pih + kk * 32 + 4);
            bw[g][kk] = pack8(u0, u1);
        }
        const float* phh = W_hh + row * 512 + lk * 8;
#pragma unroll
        for (int kk = 2; kk < 18; ++kk){
            float4 u0 = *reinterpret_cast<const float4*>(phh + (kk - 2) * 32);
            float4 u1 = *reinterpret_cast<const float4*>(phh + (kk - 2) * 32 + 4);
            bw[g][kk] = pack8(u0, u1);
        }
    }

    float bias[4];
#pragma unroll
    for (int g = 0; g < 4; ++g){
        const int col = g * 512 + hd0 + ln;
        bias[g] = b_ih[col] + b_hh[col];
    }

    // c state: lane holds rows lk*4+r (within group), col hd0+ln. f32 for all 2048 steps.
    float c0 = 0.f, c1 = 0.f, c2 = 0.f, c3 = 0.f;

    unsigned* mycnt = cnt + bg * T_STEPS;
    const int xrow = bg * 16 + ln;   // A-frag row = lane&15

    for (int t = 0; t < T_STEPS; ++t){
        // x fragments: prefetch BEFORE the sync (independent of h)
        const float* xp = x + ((size_t)xrow * T_STEPS + (size_t)t) * 64 + lk * 8;
        float4 x0a = *reinterpret_cast<const float4*>(xp);
        float4 x0b = *reinterpret_cast<const float4*>(xp + 4);
        float4 x1a = *reinterpret_cast<const float4*>(xp + 32);
        float4 x1b = *reinterpret_cast<const float4*>(xp + 36);

        if (t > 0){
            unsigned* cw = mycnt + (t - 1);
            while (__hip_atomic_load(cw, __ATOMIC_ACQUIRE, __HIP_MEMORY_SCOPE_AGENT) < NGATE)
                __builtin_amdgcn_s_sleep(2);
        }

        short8 a[18];
        a[0] = pack8(x0a, x0b);
        a[1] = pack8(x1a, x1b);
        if (t > 0){
            const unsigned short* hp =
                hbuf + (size_t)((((t & 1) ^ 1) * NGROUP + bg) * 16 + ln) * 512 + lk * 8;
#pragma unroll
            for (int kk = 2; kk < 18; ++kk)
                a[kk] = *reinterpret_cast<const short8*>(hp + (kk - 2) * 32);
        } else {
#pragma unroll
            for (int kk = 2; kk < 18; ++kk){
                short8 z = {0,0,0,0,0,0,0,0};
                a[kk] = z;
            }
        }

        floatx4 acc0 = {bias[0], bias[0], bias[0], bias[0]};
        floatx4 acc1 = {bias[1], bias[1], bias[1], bias[1]};
        floatx4 acc2 = {bias[2], bias[2], bias[2], bias[2]};
        floatx4 acc3 = {bias[3], bias[3], bias[3], bias[3]};
#pragma unroll
        for (int kk = 0; kk < 18; ++kk){
            acc0 = __builtin_amdgcn_mfma_f32_16x16x32_bf16(a[kk], bw[0][kk], acc0, 0, 0, 0);
            acc1 = __builtin_amdgcn_mfma_f32_16x16x32_bf16(a[kk], bw[1][kk], acc1, 0, 0, 0);
            acc2 = __builtin_amdgcn_mfma_f32_16x16x32_bf16(a[kk], bw[2][kk], acc2, 0, 0, 0);
            acc3 = __builtin_amdgcn_mfma_f32_16x16x32_bf16(a[kk], bw[3][kk], acc3, 0, 0, 0);
        }

        // epilogue: C/D mapping col=lane&15, row=(lane>>4)*4+reg
        unsigned short* hw =
            hbuf + (size_t)(((t & 1) * NGROUP + bg) * 16) * 512 + hd0 + ln;

#define EPI(R, CREG)                                                         \
        {   float iv = fsigmoid(acc0[R]);                                    \
            float fv = fsigmoid(acc1[R]);                                    \
            float gv = ftanh(acc2[R]);                                       \
            float ov = fsigmoid(acc3[R]);                                    \
            CREG = fv * CREG + iv * gv;                                      \
            float hv = ov * ftanh(CREG);                                     \
            hw[(lk * 4 + R) * 512] = f2bf(hv);                               \
            if (t == T_STEPS - 1){                                           \
                int rr = bg * 16 + lk * 4 + R;                               \
                out[8192  + rr * 512 + hd0 + ln] = hv;                       \
                out[40960 + rr * 512 + hd0 + ln] = CREG;                     \
            }                                                                \
        }
        EPI(0, c0) EPI(1, c1) EPI(2, c2) EPI(3, c3)
#undef EPI

        __threadfence();  // make h-slice stores visible device-wide (cross-XCD)
        if (lane == 0)
            __hip_atomic_fetch_add(mycnt + t, 1u, __ATOMIC_RELEASE, __HIP_MEMORY_SCOPE_AGENT);
    }

    // ---- pred = hT @ W_out^T + b_out, done by gate-group 0 of each batch group ----
    if (gi == 0){
        unsigned* cw = mycnt + (T_STEPS - 1);
        while (__hip_atomic_load(cw, __ATOMIC_ACQUIRE, __HIP_MEMORY_SCOPE_AGENT) < NGATE)
            __builtin_amdgcn_s_sleep(2);
        // h_{T-1} lives in slot (T-1)&1 == 1
        const unsigned short* hp =
            hbuf + (size_t)((1 * NGROUP + bg) * 16 + ln) * 512 + lk * 8;
        short8 ha[16];
#pragma unroll
        for (int kk = 0; kk < 16; ++kk)
            ha[kk] = *reinterpret_cast<const short8*>(hp + kk * 32);
#pragma unroll
        for (int o0 = 0; o0 < 8; ++o0){
            const int col = o0 * 16 + ln;
            const float* wp = W_out + col * 512 + lk * 8;
            floatx4 pa = {0.f, 0.f, 0.f, 0.f};
#pragma unroll
            for (int kk = 0; kk < 16; ++kk){
                float4 w0 = *reinterpret_cast<const float4*>(wp + kk * 32);
                float4 w1 = *reinterpret_cast<const float4*>(wp + kk * 32 + 4);
                pa = __builtin_amdgcn_mfma_f32_16x16x32_bf16(ha[kk], pack8(w0, w1), pa, 0, 0, 0);
            }
            const float bo = b_out[col];
#pragma unroll
            for (int r = 0; r < 4; ++r){
                const int rr = bg * 16 + lk * 4 + r;
                out[rr * 128 + col] = pa[r] + bo;
            }
        }
    }
}

extern "C" void kernel_launch(void* const* d_in, const int* in_sizes, int n_in,
                              void* d_out, int out_size, void* d_ws, size_t ws_size,
                              hipStream_t stream) {
    const float* x     = (const float*)d_in[0];
    const float* W_ih  = (const float*)d_in[1];
    const float* W_hh  = (const float*)d_in[2];
    const float* b_ih  = (const float*)d_in[3];
    const float* b_hh  = (const float*)d_in[4];
    const float* W_out = (const float*)d_in[5];
    const float* b_out = (const float*)d_in[6];

    // ws layout: [0,128KB) h double-buffer (bf16), [128KB,160KB) step counters
    const size_t HBUF_BYTES = (size_t)2 * NGROUP * 16 * 512 * 2;
    unsigned short* hbuf = (unsigned short*)d_ws;
    unsigned* cnt = (unsigned*)((char*)d_ws + HBUF_BYTES);

    hipMemsetAsync(cnt, 0, NGROUP * T_STEPS * sizeof(unsigned), stream);
    lstm_persist<<<dim3(NGROUP * NGATE), dim3(64), 0, stream>>>(
        x, W_ih, W_hh, b_ih, b_hh, W_out, b_out,
        (float*)d_out, hbuf, cnt);
}

// Round 2
// 7334.917 us; speedup vs baseline: 2.3369x; 2.3369x over previous
//
#include <hip/hip_runtime.h>
#include <hip/hip_bf16.h>

// LSTM persistent kernel, MI355X. B=64, T=2048, D=64, H=512, O=128. K=D+H=576.
// 128 one-wave WGs: bg = blockIdx&3 (16 batch rows, clusters a bg onto 2 XCDs
// under round-robin dispatch), gi = blockIdx>>2 (16 hidden dims = 64 gate rows).
// Weights stationary in VGPRs/AGPRs. Cross-WG h broadcast + epoch flags use
// L2-bypassing sc0 sc1 loads/stores (L3 is coherent across XCDs) -> no
// buffer_inv / buffer_wbl2 anywhere; x and weights stay L2-cached.

typedef short short8 __attribute__((ext_vector_type(8)));
typedef float floatx4 __attribute__((ext_vector_type(4)));

#define T_STEPS 2048
#define NBG 4
#define NGI 32

__device__ __forceinline__ unsigned short f2bf(float f){
    unsigned u = __builtin_bit_cast(unsigned, f);
    u += 0x7FFFu + ((u >> 16) & 1u);   // RNE; inputs finite
    return (unsigned short)(u >> 16);
}

__device__ __forceinline__ short8 pack8(float4 a, float4 b){
    short8 s;
    s[0]=(short)f2bf(a.x); s[1]=(short)f2bf(a.y); s[2]=(short)f2bf(a.z); s[3]=(short)f2bf(a.w);
    s[4]=(short)f2bf(b.x); s[5]=(short)f2bf(b.y); s[6]=(short)f2bf(b.z); s[7]=(short)f2bf(b.w);
    return s;
}

__device__ __forceinline__ float fsigmoid(float x){ return 1.0f/(1.0f+__expf(-x)); }
__device__ __forceinline__ float ftanh(float x){ return 2.0f*fsigmoid(2.0f*x)-1.0f; }

// 16 L2-bypassing 16B loads (stride 64B), single trailing wait.
#define HLOAD16(A0, BASE) \
    asm volatile( \
        "global_load_dwordx4 %0, %16, off sc0 sc1\n\t" \
        "global_load_dwordx4 %1, %16, off offset:64 sc0 sc1\n\t" \
        "global_load_dwordx4 %2, %16, off offset:128 sc0 sc1\n\t" \
        "global_load_dwordx4 %3, %16, off offset:192 sc0 sc1\n\t" \
        "global_load_dwordx4 %4, %16, off offset:256 sc0 sc1\n\t" \
        "global_load_dwordx4 %5, %16, off offset:320 sc0 sc1\n\t" \
        "global_load_dwordx4 %6, %16, off offset:384 sc0 sc1\n\t" \
        "global_load_dwordx4 %7, %16, off offset:448 sc0 sc1\n\t" \
        "global_load_dwordx4 %8, %16, off offset:512 sc0 sc1\n\t" \
        "global_load_dwordx4 %9, %16, off offset:576 sc0 sc1\n\t" \
        "global_load_dwordx4 %10, %16, off offset:640 sc0 sc1\n\t" \
        "global_load_dwordx4 %11, %16, off offset:704 sc0 sc1\n\t" \
        "global_load_dwordx4 %12, %16, off offset:768 sc0 sc1\n\t" \
        "global_load_dwordx4 %13, %16, off offset:832 sc0 sc1\n\t" \
        "global_load_dwordx4 %14, %16, off offset:896 sc0 sc1\n\t" \
        "global_load_dwordx4 %15, %16, off offset:960 sc0 sc1\n\t" \
        "s_waitcnt vmcnt(0)" \
        : "=&v"((A0)[0]), "=&v"((A0)[1]), "=&v"((A0)[2]), "=&v"((A0)[3]), \
          "=&v"((A0)[4]), "=&v"((A0)[5]), "=&v"((A0)[6]), "=&v"((A0)[7]), \
          "=&v"((A0)[8]), "=&v"((A0)[9]), "=&v"((A0)[10]), "=&v"((A0)[11]), \
          "=&v"((A0)[12]), "=&v"((A0)[13]), "=&v"((A0)[14]), "=&v"((A0)[15]) \
        : "v"(BASE) : "memory")

__global__ __launch_bounds__(64, 1)
void lstm_persist(const float* __restrict__ x,
                  const float* __restrict__ W_ih,
                  const float* __restrict__ W_hh,
                  const float* __restrict__ b_ih,
                  const float* __restrict__ b_hh,
                  const float* __restrict__ W_out,
                  const float* __restrict__ b_out,
                  float* __restrict__ out,
                  unsigned short* __restrict__ hbuf,  // [2][64][512] bf16
                  unsigned* __restrict__ flags)       // [NBG][NGI] epochs
{
    const int wg   = blockIdx.x;
    const int bg   = wg & 3;         // batch group (16 rows) -> XCDs {bg, bg+4}
    const int gi   = wg >> 2;        // gate group (16 hidden dims)
    const int lane = threadIdx.x;    // 0..63
    const int ln   = lane & 15;
    const int lk   = lane >> 4;      // k-chunk 0..3
    const int hd0  = gi << 4;

    __shared__ __align__(16) unsigned short hl[256];   // 16x16 bf16 transpose tile

    // ---- stationary B fragments (weights) ----
    short8 bw[4][18];
#pragma unroll
    for (int g = 0; g < 4; ++g){
        const int row = g * 512 + hd0 + ln;
        const float* pih = W_ih + row * 64 + lk * 8;
#pragma unroll
        for (int kk = 0; kk < 2; ++kk){
            float4 u0 = *reinterpret_cast<const float4*>(pih + kk * 32);
            float4 u1 = *reinterpret_cast<const float4*>(pih + kk * 32 + 4);
            bw[g][kk] = pack8(u0, u1);
        }
        const float* phh = W_hh + row * 512 + lk * 8;
#pragma unroll
        for (int kk = 2; kk < 18; ++kk){
            float4 u0 = *reinterpret_cast<const float4*>(phh + (kk - 2) * 32);
            float4 u1 = *reinterpret_cast<const float4*>(phh + (kk - 2) * 32 + 4);
            bw[g][kk] = pack8(u0, u1);
        }
    }

    float bias[4];
#pragma unroll
    for (int g = 0; g < 4; ++g){
        const int col = g * 512 + hd0 + ln;
        bias[g] = b_ih[col] + b_hh[col];
    }

    float c0 = 0.f, c1 = 0.f, c2 = 0.f, c3 = 0.f;

    unsigned* fbase = flags + bg * NGI;
    const unsigned* fpoll = fbase + (lane & 31);
    unsigned* fme = fbase + gi;
    const int xrow = bg * 16 + ln;

    for (int t = 0; t < T_STEPS; ++t){
        // x fragments: issue BEFORE the spin (independent of h); normal cached loads
        const float* xp = x + ((size_t)xrow * T_STEPS + (size_t)t) * 64 + lk * 8;
        float4 x0a = *reinterpret_cast<const float4*>(xp);
        float4 x0b = *reinterpret_cast<const float4*>(xp + 4);
        float4 x1a = *reinterpret_cast<const float4*>(xp + 32);
        float4 x1b = *reinterpret_cast<const float4*>(xp + 36);

        if (t > 0){
            unsigned fv;
            do {
                asm volatile("global_load_dword %0, %1, off sc0 sc1\n\t"
                             "s_waitcnt vmcnt(0)"
                             : "=v"(fv) : "v"(fpoll) : "memory");
            } while (!__all((int)(fv >= (unsigned)t)));
        }

        short8 a[18];
        a[0] = pack8(x0a, x0b);
        a[1] = pack8(x1a, x1b);
        if (t > 0){
            const unsigned short* hp =
                hbuf + (size_t)((((t & 1) ^ 1) * 4 + bg) * 16 + ln) * 512 + lk * 8;
            short8* hA = &a[2];
            HLOAD16(hA, hp);
        } else {
#pragma unroll
            for (int kk = 2; kk < 18; ++kk){
                short8 z = {0,0,0,0,0,0,0,0};
                a[kk] = z;
            }
        }

        floatx4 acc0 = {bias[0], bias[0], bias[0], bias[0]};
        floatx4 acc1 = {bias[1], bias[1], bias[1], bias[1]};
        floatx4 acc2 = {bias[2], bias[2], bias[2], bias[2]};
        floatx4 acc3 = {bias[3], bias[3], bias[3], bias[3]};
#pragma unroll
        for (int kk = 0; kk < 18; ++kk){
            acc0 = __builtin_amdgcn_mfma_f32_16x16x32_bf16(a[kk], bw[0][kk], acc0, 0, 0, 0);
            acc1 = __builtin_amdgcn_mfma_f32_16x16x32_bf16(a[kk], bw[1][kk], acc1, 0, 0, 0);
            acc2 = __builtin_amdgcn_mfma_f32_16x16x32_bf16(a[kk], bw[2][kk], acc2, 0, 0, 0);
            acc3 = __builtin_amdgcn_mfma_f32_16x16x32_bf16(a[kk], bw[3][kk], acc3, 0, 0, 0);
        }

        // epilogue: C/D mapping col=lane&15, row=(lane>>4)*4+reg
#define EPI(R, CREG)                                                         \
        {   float iv = fsigmoid(acc0[R]);                                    \
            float fv_ = fsigmoid(acc1[R]);                                   \
            float gv = ftanh(acc2[R]);                                       \
            float ov = fsigmoid(acc3[R]);                                    \
            CREG = fv_ * CREG + iv * gv;                                     \
            float hv = ov * ftanh(CREG);                                     \
            hl[(lk * 4 + R) * 16 + ln] = f2bf(hv);                           \
            if (t == T_STEPS - 1){                                           \
                int rr = bg * 16 + lk * 4 + R;                               \
                out[8192  + rr * 512 + hd0 + ln] = hv;                       \
                out[40960 + rr * 512 + hd0 + ln] = CREG;                     \
            }                                                                \
        }
        EPI(0, c0) EPI(1, c1) EPI(2, c2) EPI(3, c3)
#undef EPI

        asm volatile("s_waitcnt lgkmcnt(0)" ::: "memory");

        // transposed h store: 32 lanes x 16B, write-through to L3
        if (lane < 32){
            const int row = lane >> 1, half = lane & 1;
            short8 v = *reinterpret_cast<const short8*>(&hl[row * 16 + half * 8]);
            unsigned short* dst =
                hbuf + (size_t)(((t & 1) * 4 + bg) * 16 + row) * 512 + hd0 + half * 8;
            asm volatile("global_store_dwordx4 %0, %1, off sc0 sc1"
                         :: "v"(dst), "v"(v) : "memory");
        }
        asm volatile("s_waitcnt vmcnt(0)" ::: "memory");
        if (lane == 0){
            unsigned ep = (unsigned)(t + 1);
            asm volatile("global_store_dword %0, %1, off sc0 sc1"
                         :: "v"(fme), "v"(ep) : "memory");
        }
    }

    // ---- pred = hT @ W_out^T + b_out (gate-group 0 of each batch group) ----
    if (gi == 0){
        unsigned fv;
        do {
            asm volatile("global_load_dword %0, %1, off sc0 sc1\n\t"
                         "s_waitcnt vmcnt(0)"
                         : "=v"(fv) : "v"(fpoll) : "memory");
        } while (!__all((int)(fv >= (unsigned)T_STEPS)));

        // h_{T-1} is in slot 1
        const unsigned short* hp =
            hbuf + (size_t)((1 * 4 + bg) * 16 + ln) * 512 + lk * 8;
        short8 ha[16];
        HLOAD16(ha, hp);
#pragma unroll
        for (int o0 = 0; o0 < 8; ++o0){
            const int col = o0 * 16 + ln;
            const float* wp = W_out + col * 512 + lk * 8;
            floatx4 pa = {0.f, 0.f, 0.f, 0.f};
#pragma unroll
            for (int kk = 0; kk < 16; ++kk){
                float4 w0 = *reinterpret_cast<const float4*>(wp + kk * 32);
                float4 w1 = *reinterpret_cast<const float4*>(wp + kk * 32 + 4);
                pa = __builtin_amdgcn_mfma_f32_16x16x32_bf16(ha[kk], pack8(w0, w1), pa, 0, 0, 0);
            }
            const float bo = b_out[col];
#pragma unroll
            for (int r = 0; r < 4; ++r){
                const int rr = bg * 16 + lk * 4 + r;
                out[rr * 128 + col] = pa[r] + bo;
            }
        }
    }
}

extern "C" void kernel_launch(void* const* d_in, const int* in_sizes, int n_in,
                              void* d_out, int out_size, void* d_ws, size_t ws_size,
                              hipStream_t stream) {
    const float* x     = (const float*)d_in[0];
    const float* W_ih  = (const float*)d_in[1];
    const float* W_hh  = (const float*)d_in[2];
    const float* b_ih  = (const float*)d_in[3];
    const float* b_hh  = (const float*)d_in[4];
    const float* W_out = (const float*)d_in[5];
    const float* b_out = (const float*)d_in[6];

    // ws: [0,128KB) h double-buffer bf16, [128KB, +512B) epoch flags
    const size_t HBUF_BYTES = (size_t)2 * 64 * 512 * 2;
    unsigned short* hbuf = (unsigned short*)d_ws;
    unsigned* flags = (unsigned*)((char*)d_ws + HBUF_BYTES);

    hipMemsetAsync(flags, 0, NBG * NGI * sizeof(unsigned), stream);
    lstm_persist<<<dim3(NBG * NGI), dim3(64), 0, stream>>>(
        x, W_ih, W_hh, b_ih, b_hh, W_out, b_out,
        (float*)d_out, hbuf, flags);
}